// Round 10
// baseline (317.432 us; speedup 1.0000x reference)
//
#include <hip/hip_runtime.h>
#include <math.h>

#define BB 16
#define SS 16
#define VVV 64
#define EE 64
#define HHH 8
#define NLAYER 4
#define DFF_ 2048
#define LL 1024   /* S*V */
#define BL 16384  /* B*L */
#define PERL 131072  /* 64*2048 elems per layer of W1 (and W2); 32 tiles*4096 */

typedef __attribute__((ext_vector_type(8))) _Float16 half8;
typedef __attribute__((ext_vector_type(4))) _Float16 half4v;
typedef __attribute__((ext_vector_type(2))) _Float16 half2v;
typedef __attribute__((ext_vector_type(4))) float f32x4;

#if defined(__has_builtin)
#if __has_builtin(__builtin_amdgcn_fdot2)
#define HAVE_FDOT2 1
#endif
#endif

// XOR-swizzled index into row-major fp16 LDS tiles with 64-half (128 B) rows.
#define SW64(m, k)  (((m) << 6) + ((((k) >> 3) ^ ((m) & 7)) << 3) + ((k) & 7))

// Fragment-linear tile layout (64x64 fp16 = 8 frags of 512 halves):
//   A[m][k] -> frag = (m>>4)*2 + (k>>5); lane = ((k>>3)&3)*16 + (m&15); +(k&7)
// Wave loading frag f reads tile_base + f*512 + lane*8 -> contiguous 1 KB.

// ---------------- prep: weights -> fp16 fragment-linear tiles (one dispatch) ----------
__global__ __launch_bounds__(256) void k_prep(
    const float* __restrict__ W1, const float* __restrict__ W2,
    const float* __restrict__ Wqkv, const float* __restrict__ Wo,
    const float* __restrict__ Wcomb,
    _Float16* __restrict__ w1f, _Float16* __restrict__ w2f,
    _Float16* __restrict__ wqkvf, _Float16* __restrict__ wof,
    _Float16* __restrict__ wcombt)
{
  __shared__ float t[64 * 65];
  int bx = blockIdx.x;
  int cc = threadIdx.x & 63, rr = threadIdx.x >> 6;

  if (bx >= 272) {  // Wcomb [80][64] -> wcombt [64][80]
    int r0 = (bx - 272) * 64;
#pragma unroll
    for (int i = 0; i < 16; i++) {
      int r = i * 4 + rr;
      if (r0 + r < 80) t[r * 65 + cc] = Wcomb[(size_t)(r0 + r) * 64 + cc];
    }
    __syncthreads();
#pragma unroll
    for (int i = 0; i < 16; i++) {
      int c = i * 4 + rr;
      if (r0 + c < 80) wcombt[(size_t)cc * 80 + r0 + c] = (_Float16)t[c * 65 + cc];
    }
    return;
  }

  const float* src; _Float16* dst; int astr;
  if (bx < 128) {        // W1 [64 k][2048 hid]: tile g = hid block
    int l = bx >> 5, g = bx & 31;
    src = W1 + (size_t)l * PERL + g * 64; astr = 2048;
    dst = w1f + (size_t)(l * 32 + g) * 4096;
  } else if (bx < 256) { // W2 [2048 k][64 n]: tile g = k block
    int j = bx - 128; int l = j >> 5, g = j & 31;
    src = W2 + (size_t)l * PERL + (size_t)g * 64 * 64; astr = 64;
    dst = w2f + (size_t)(l * 32 + g) * 4096;
  } else if (bx < 268) { // Wqkv [64 k][192 n]: 3 tiles per layer
    int j = bx - 256; int l = j / 3, g = j % 3;
    src = Wqkv + (size_t)l * 64 * 192 + g * 64; astr = 192;
    dst = wqkvf + (size_t)(l * 3 + g) * 4096;
  } else {               // Wo [64 k][64 n]
    int l = bx - 268;
    src = Wo + (size_t)l * 4096; astr = 64;
    dst = wof + (size_t)l * 4096;
  }
#pragma unroll
  for (int i = 0; i < 16; i++) {
    int a = i * 4 + rr;
    t[cc * 65 + a] = src[(size_t)a * astr + cc];  // t[m][k] = S[k][m]
  }
  __syncthreads();
#pragma unroll
  for (int it = 0; it < 2; it++) {
    int c = threadIdx.x + it * 256;
    int frag = c >> 6, lane = c & 63;
    int m = (frag >> 1) * 16 + (lane & 15);
    int k0 = (frag & 1) * 32 + (lane >> 4) * 8;
    const float* tr = &t[m * 65 + k0];
    half8 h;
#pragma unroll
    for (int j = 0; j < 8; j++) h[j] = (_Float16)tr[j];
    *(half8*)&dst[(size_t)c * 8] = h;
  }
}

// ---- shared QKV GEMM body for one n-block; q/k/v all stored head-major [b][h][row][8] ----
__device__ __forceinline__ void qkv_nb(
    const half8 (&af)[2][2], const _Float16* __restrict__ wqkvf,
    const float* __restrict__ bqkv, _Float16* __restrict__ qbuf,
    _Float16* __restrict__ kbuf, _Float16* __restrict__ vbuf,
    int bx, int nb, int wm, int wn, int lane)
{
  int quad = lane >> 4, l15 = lane & 15;
  const _Float16* bt = wqkvf + (size_t)nb * 4096;
  half8 bf[2][2];
#pragma unroll
  for (int nt = 0; nt < 2; nt++)
#pragma unroll
    for (int ks = 0; ks < 2; ks++)
      bf[nt][ks] = *(const half8*)&bt[(size_t)(((wn * 2 + nt) * 2 + ks) * 512) +
                                      lane * 8];
  f32x4 acc[2][2];
#pragma unroll
  for (int mt = 0; mt < 2; mt++)
#pragma unroll
    for (int nt = 0; nt < 2; nt++) {
      float bv = bqkv[nb * 64 + wn * 32 + nt * 16 + l15];
      acc[mt][nt] = (f32x4){bv, bv, bv, bv};
    }
#pragma unroll
  for (int ks = 0; ks < 2; ks++)
#pragma unroll
    for (int mt = 0; mt < 2; mt++)
#pragma unroll
      for (int nt = 0; nt < 2; nt++)
        acc[mt][nt] = __builtin_amdgcn_mfma_f32_16x16x32_f16(
            af[mt][ks], bf[nt][ks], acc[mt][nt], 0, 0, 0);
  _Float16* dst = (nb == 0) ? qbuf : ((nb == 1) ? kbuf : vbuf);
#pragma unroll
  for (int mt = 0; mt < 2; mt++)
#pragma unroll
    for (int nt = 0; nt < 2; nt++) {
      int col = wn * 32 + nt * 16 + l15;
      int h = col >> 3, d = col & 7;
#pragma unroll
      for (int r = 0; r < 4; r++) {
        int row = bx * 64 + wm * 32 + mt * 16 + quad * 4 + r;
        int b = row >> 10, rb = row & 1023;
        dst[((size_t)(b * 8 + h) * 1024 + rb) * 8 + d] = (_Float16)acc[mt][nt][r];
      }
    }
}

// ---- FFN helpers: explicit register stages (NO dynamic register-array indexing) ----
__device__ __forceinline__ void ffn_load(
    const _Float16* __restrict__ w1f, const _Float16* __restrict__ w2f, int g,
    half8 (&a1)[2][2], half8 (&b2w)[2][2], int wm, int wn, int lane)
{
  const _Float16* w1t_ = w1f + (size_t)g * 4096;
  const _Float16* w2t_ = w2f + (size_t)g * 4096;
#pragma unroll
  for (int ht = 0; ht < 2; ht++)
#pragma unroll
    for (int ks = 0; ks < 2; ks++)
      a1[ht][ks] = *(const half8*)&w1t_[(size_t)(((wm * 2 + ht) * 2 + ks) * 512) +
                                        lane * 8];
#pragma unroll
  for (int nt = 0; nt < 2; nt++)
#pragma unroll
    for (int ks = 0; ks < 2; ks++)
      b2w[nt][ks] = *(const half8*)&w2t_[(size_t)(((wn * 2 + nt) * 2 + ks) * 512) +
                                         lane * 8];
}

__device__ __forceinline__ void ffn_step(
    const half8 (&a1)[2][2], const half8 (&b2w)[2][2], const half8 (&xb)[2][2],
    _Float16* hsbuf, const float* __restrict__ b1, int g, f32x4 (&acc)[2][2],
    int wm, int wn, int lane)
{
  int quad = lane >> 4, l15 = lane & 15;
  f32x4 hacc[2][2];
#pragma unroll
  for (int ht = 0; ht < 2; ht++)
#pragma unroll
    for (int mt = 0; mt < 2; mt++) hacc[ht][mt] = (f32x4){0.f, 0.f, 0.f, 0.f};
#pragma unroll
  for (int ks = 0; ks < 2; ks++)
#pragma unroll
    for (int ht = 0; ht < 2; ht++)
#pragma unroll
      for (int mt = 0; mt < 2; mt++)
        hacc[ht][mt] = __builtin_amdgcn_mfma_f32_16x16x32_f16(
            a1[ht][ks], xb[mt][ks], hacc[ht][mt], 0, 0, 0);
#pragma unroll
  for (int ht = 0; ht < 2; ht++) {
    float4 bb = *(const float4*)&b1[g * 64 + wm * 32 + ht * 16 + quad * 4];
#pragma unroll
    for (int mt = 0; mt < 2; mt++) {
      f32x4 hv = hacc[ht][mt];
      half4v hp = (half4v){
          (_Float16)fmaxf(hv[0] + bb.x, 0.f), (_Float16)fmaxf(hv[1] + bb.y, 0.f),
          (_Float16)fmaxf(hv[2] + bb.z, 0.f), (_Float16)fmaxf(hv[3] + bb.w, 0.f)};
      *(half4v*)&hsbuf[SW64(wn * 32 + mt * 16 + l15,
                            wm * 32 + ht * 16 + quad * 4)] = hp;
    }
  }
  __syncthreads();
#pragma unroll
  for (int ks = 0; ks < 2; ks++)
#pragma unroll
    for (int mt = 0; mt < 2; mt++) {
      half8 a2 = *(const half8*)&hsbuf[SW64(wm * 32 + mt * 16 + l15,
                                            ks * 32 + quad * 8)];
#pragma unroll
      for (int nt = 0; nt < 2; nt++)
        acc[mt][nt] = __builtin_amdgcn_mfma_f32_16x16x32_f16(a2, b2w[nt][ks],
                                                             acc[mt][nt], 0, 0, 0);
    }
}

// ------- fused embed + comb GEMM + pos/type + QKV(layer0): writes x1, zm, q/k/v -------
__global__ __launch_bounds__(256) void k_embqkv(
    const float* __restrict__ features, const int* __restrict__ ovtag,
    const int* __restrict__ poiid, const float* __restrict__ W_raw,
    const float* __restrict__ b_raw, const float* __restrict__ ov_tab,
    const float* __restrict__ poi_tab, const _Float16* __restrict__ wcombt,
    const float* __restrict__ b_comb, const float* __restrict__ pos_tab,
    const float* __restrict__ type_tab, float* __restrict__ x1,
    float* __restrict__ zm, const _Float16* __restrict__ wqkvf,
    const float* __restrict__ bqkv, _Float16* __restrict__ qbuf,
    _Float16* __restrict__ kbuf, _Float16* __restrict__ vbuf)
{
  constexpr int KP = 104;
  __shared__ _Float16 As[64 * KP];
  __shared__ _Float16 Bs[64 * KP];
  __shared__ _Float16 xs[4096];
  int tid = threadIdx.x;
  int bx = blockIdx.x;
  int m0 = bx * 64;
  int wave = tid >> 6, lane = tid & 63, quad = lane >> 4, l15 = lane & 15;
  int wm = wave >> 1, wn = wave & 1;
  for (int p = tid; p < 1536; p += 256) {
    int r = p / 24, s = p - r * 24; int c = s * 4;
    int row = m0 + r;
    float f0 = features[row * 3 + 0];
    float f1 = features[row * 3 + 1];
    float f2 = features[row * 3 + 2];
    if (s == 0) zm[row] = ((f0 + f1 + f2) == 0.f) ? 1.f : 0.f;
    half4v h;
#pragma unroll
    for (int j = 0; j < 4; j++) {
      int cc = c + j; float v;
      if (cc < 64) {
        v = b_raw[cc] + f0 * W_raw[cc] + f1 * W_raw[64 + cc] + f2 * W_raw[128 + cc];
      } else if (cc < 72) {
        int tt = ovtag[row]; v = (tt <= 0) ? 0.f : ov_tab[tt * 8 + cc - 64];
      } else if (cc < 80) {
        int tt = poiid[row]; v = (tt <= 0) ? 0.f : poi_tab[tt * 8 + cc - 72];
      } else v = 0.f;
      h[j] = (_Float16)v;
    }
    *(half4v*)&As[r * KP + c] = h;
  }
  for (int p = tid; p < 1536; p += 256) {
    int r = p / 24, s = p - r * 24; int c = s * 4;
    half4v h = (half4v){0, 0, 0, 0};
    if (c < 80) h = *(const half4v*)&wcombt[r * 80 + c];
    *(half4v*)&Bs[r * KP + c] = h;
  }
  __syncthreads();
  f32x4 acc[2][2];
#pragma unroll
  for (int mt = 0; mt < 2; mt++)
#pragma unroll
    for (int nt = 0; nt < 2; nt++) {
      float bv = b_comb[wn * 32 + nt * 16 + l15];
      acc[mt][nt] = (f32x4){bv, bv, bv, bv};
    }
#pragma unroll
  for (int ks = 0; ks < 3; ks++) {
    half8 af[2], bf[2];
#pragma unroll
    for (int mt = 0; mt < 2; mt++)
      af[mt] = *(const half8*)&As[(wm * 32 + mt * 16 + l15) * KP + ks * 32 + quad * 8];
#pragma unroll
    for (int nt = 0; nt < 2; nt++)
      bf[nt] = *(const half8*)&Bs[(wn * 32 + nt * 16 + l15) * KP + ks * 32 + quad * 8];
#pragma unroll
    for (int mt = 0; mt < 2; mt++)
#pragma unroll
      for (int nt = 0; nt < 2; nt++)
        acc[mt][nt] = __builtin_amdgcn_mfma_f32_16x16x32_f16(af[mt], bf[nt],
                                                             acc[mt][nt], 0, 0, 0);
  }
#pragma unroll
  for (int mt = 0; mt < 2; mt++)
#pragma unroll
    for (int nt = 0; nt < 2; nt++)
#pragma unroll
      for (int r = 0; r < 4; r++) {
        int lrow = wm * 32 + mt * 16 + quad * 4 + r;
        int row = m0 + lrow;
        int col = wn * 32 + nt * 16 + l15;
        int l = row & (LL - 1);
        float v = acc[mt][nt][r] +
            pos_tab[(l >> 6) * 64 + col] + type_tab[(l & 63) * 64 + col];
        x1[(size_t)row * 64 + col] = v;
        xs[SW64(lrow, col)] = (_Float16)v;
      }
  __syncthreads();
  half8 af[2][2];
#pragma unroll
  for (int mt = 0; mt < 2; mt++)
#pragma unroll
    for (int ks = 0; ks < 2; ks++)
      af[mt][ks] = *(const half8*)&xs[SW64(wm * 32 + mt * 16 + l15,
                                           ks * 32 + quad * 8)];
  for (int nb = 0; nb < 3; nb++)
    qkv_nb(af, wqkvf, bqkv, qbuf, kbuf, vbuf, bx, nb, wm, wn, lane);
}

// ------- attention: all-coalesced staging; output in A-fragment-linear layout -------
__global__ __launch_bounds__(256) void k_attn2(
    const _Float16* __restrict__ qbuf, const _Float16* __restrict__ kbuf,
    const _Float16* __restrict__ vbuf, const float* __restrict__ zm,
    _Float16* __restrict__ obuf)
{
  __shared__ _Float16 Ks[1024 * 8];
  __shared__ _Float16 Vs[1024 * 8];
  __shared__ float zs[1024];
  int blk = blockIdx.x;
  int qb = blk & 3, h = (blk >> 2) & 7, b = blk >> 5;
  int qrow = qb * 256 + threadIdx.x;
  // coalesced q load (head-major), independent of staging
  half8 qh = *(const half8*)&qbuf[(size_t)(b * 8 + h) * 8192 + (size_t)qrow * 8];
  const _Float16* kb = kbuf + (size_t)(b * 8 + h) * 8192;
  const _Float16* vb = vbuf + (size_t)(b * 8 + h) * 8192;
  for (int p = threadIdx.x; p < 1024; p += 256) {
    *(half8*)&Ks[p * 8] = *(const half8*)&kb[p * 8];
    *(half8*)&Vs[p * 8] = *(const half8*)&vb[p * 8];
    zs[p] = zm[b * LL + p];
  }
  __syncthreads();
  int tq = qrow >> 6, vq = qrow & 63;
  const float scale = 0.3535533905932738f;
  float m = -INFINITY, lsum = 0.f;
  float acc[8] = {0.f, 0.f, 0.f, 0.f, 0.f, 0.f, 0.f, 0.f};
  bool zmq = (zs[qrow] != 0.f);

  auto attend = [&](int k) {
    if (zs[k] != 0.f) return;
    half8 kk = *(const half8*)&Ks[k * 8];
    float s = 0.f;
#ifdef HAVE_FDOT2
#pragma unroll
    for (int j = 0; j < 4; j++) {
      half2v qa = (half2v){qh[2 * j], qh[2 * j + 1]};
      half2v ka = (half2v){kk[2 * j], kk[2 * j + 1]};
      s = __builtin_amdgcn_fdot2(qa, ka, s, false);
    }
#else
#pragma unroll
    for (int j = 0; j < 8; j++) s += (float)qh[j] * (float)kk[j];
#endif
    s *= scale;
    half8 vv = *(const half8*)&Vs[k * 8];
    if (s <= m) {
      float p = __expf(s - m);
      lsum += p;
#pragma unroll
      for (int d = 0; d < 8; d++) acc[d] += p * (float)vv[d];
    } else {
      float r = __expf(m - s);
      lsum = lsum * r + 1.f;
#pragma unroll
      for (int d = 0; d < 8; d++) acc[d] = acc[d] * r + (float)vv[d];
      m = s;
    }
  };

  if (!zmq) {
    for (int vv = 0; vv < 64; vv++) attend(tq * 64 + vv);
    for (int tt = 0; tt < 16; tt++) {
      if (tt == tq) continue;
      attend(tt * 64 + vq);
    }
  }
  float inv = 1.f / lsum;
  half8 o;
#pragma unroll
  for (int d = 0; d < 8; d++) o[d] = (_Float16)(acc[d] * inv);
  size_t tile = (size_t)(b * 16 + (qrow >> 6));
  int frag = ((qrow >> 4) & 3) * 2 + (h >> 2);
  int flane = (h & 3) * 16 + (qrow & 15);
  *(half8*)&obuf[tile * 4096 + frag * 512 + flane * 8] = o;
}

// ---- layer megakernel (512 thr): oln + LN1 + full FFN + LN2 + next QKV (or head) ----
__global__ __launch_bounds__(512) void k_layer(
    const _Float16* __restrict__ obuf, const _Float16* __restrict__ wof,
    const float* __restrict__ bo, float* __restrict__ x1,
    const float* __restrict__ ln1_s, const float* __restrict__ ln1_b,
    const _Float16* __restrict__ w1f, const _Float16* __restrict__ w2f,
    const float* __restrict__ b1, const float* __restrict__ b2,
    const float* __restrict__ ln2_s, const float* __restrict__ ln2_b,
    const _Float16* __restrict__ wqkvf, const float* __restrict__ bqkv,
    _Float16* __restrict__ qbuf, _Float16* __restrict__ kbuf,
    _Float16* __restrict__ vbuf, int doqkv,
    const float* __restrict__ Wh, const float* __restrict__ bh,
    float* __restrict__ out)
{
  __shared__ float ots[64 * 68];          // 17.4 KB
  __shared__ _Float16 xs[4096];           // 8 KB
  __shared__ float x2f[4096];             // 16 KB
  __shared__ _Float16 hs[2][2][4096];     // 32 KB ([grp][dbuf])
  int tid = threadIdx.x;
  int bx = blockIdx.x;
  int wave = tid >> 6, lane = tid & 63;
  int quad = lane >> 4, l15 = lane & 15;
  int grp = wave >> 2, w4 = wave & 3;
  int wm = w4 >> 1, wn = w4 & 1;

  // ---- o-proj (8 waves: m-quarter = grp*2+wm, n-half = wn) ----
  {
    const _Float16* ot = obuf + (size_t)bx * 4096;
    int mq = grp * 2 + wm;
    half8 af[2], bf[2][2];
#pragma unroll
    for (int ks = 0; ks < 2; ks++)
      af[ks] = *(const half8*)&ot[(size_t)((mq * 2 + ks) * 512) + lane * 8];
#pragma unroll
    for (int nt = 0; nt < 2; nt++)
#pragma unroll
      for (int ks = 0; ks < 2; ks++)
        bf[nt][ks] = *(const half8*)&wof[(size_t)(((wn * 2 + nt) * 2 + ks) * 512) +
                                         lane * 8];
    f32x4 acc[2];
#pragma unroll
    for (int nt = 0; nt < 2; nt++) {
      float bv = bo[wn * 32 + nt * 16 + l15];
      acc[nt] = (f32x4){bv, bv, bv, bv};
    }
#pragma unroll
    for (int ks = 0; ks < 2; ks++)
#pragma unroll
      for (int nt = 0; nt < 2; nt++)
        acc[nt] = __builtin_amdgcn_mfma_f32_16x16x32_f16(af[ks], bf[nt][ks],
                                                         acc[nt], 0, 0, 0);
#pragma unroll
    for (int nt = 0; nt < 2; nt++)
#pragma unroll
      for (int r = 0; r < 4; r++)
        ots[(mq * 16 + quad * 4 + r) * 68 + wn * 32 + nt * 16 + l15] = acc[nt][r];
  }
  __syncthreads();
  // ---- residual + LN1 (8 waves x 8 rows) ----
  for (int i = 0; i < 8; i++) {
    int row = wave * 8 + i;
    size_t off = (size_t)(bx * 64 + row) * 64 + lane;
    float val = ots[row * 68 + lane] + x1[off];
    float sum = val;
#pragma unroll
    for (int o = 32; o > 0; o >>= 1) sum += __shfl_xor(sum, o);
    float mean = sum * (1.f / 64.f);
    float d = val - mean;
    float sq = d * d;
#pragma unroll
    for (int o = 32; o > 0; o >>= 1) sq += __shfl_xor(sq, o);
    float xv = d * rsqrtf(sq * (1.f / 64.f) + 1e-5f) * ln1_s[lane] + ln1_b[lane];
    x2f[row * 64 + lane] = xv;
    xs[SW64(row, lane)] = (_Float16)xv;
  }
  __syncthreads();

  // ---- FFN, full hidden; group g handles chunks 2i+g; explicit 2-stage pipeline ----
  half8 xb[2][2];
#pragma unroll
  for (int mt = 0; mt < 2; mt++)
#pragma unroll
    for (int ks = 0; ks < 2; ks++)
      xb[mt][ks] = *(const half8*)&xs[SW64(wn * 32 + mt * 16 + l15,
                                           ks * 32 + quad * 8)];
  f32x4 acc[2][2];
#pragma unroll
  for (int mt = 0; mt < 2; mt++)
#pragma unroll
    for (int nt = 0; nt < 2; nt++) {
      float bv = (grp == 0) ? b2[wn * 32 + nt * 16 + l15] : 0.f;
      acc[mt][nt] = (f32x4){bv, bv, bv, bv};
    }
  half8 a1x[2][2], b2x[2][2], a1y[2][2], b2y[2][2];
  ffn_load(w1f, w2f, grp, a1x, b2x, wm, wn, lane);
  for (int ii = 0; ii < 8; ii++) {
    ffn_load(w1f, w2f, ii * 4 + 2 + grp, a1y, b2y, wm, wn, lane);
    ffn_step(a1x, b2x, xb, &hs[grp][0][0], b1, ii * 4 + grp, acc, wm, wn, lane);
    if (ii < 7) ffn_load(w1f, w2f, ii * 4 + 4 + grp, a1x, b2x, wm, wn, lane);
    ffn_step(a1y, b2y, xb, &hs[grp][1][0], b1, ii * 4 + 2 + grp, acc, wm, wn, lane);
  }
  // ---- cross-group reduce into ots ----
  __syncthreads();
  if (grp == 0) {
#pragma unroll
    for (int mt = 0; mt < 2; mt++)
#pragma unroll
      for (int nt = 0; nt < 2; nt++)
#pragma unroll
        for (int r = 0; r < 4; r++)
          ots[(wm * 32 + mt * 16 + quad * 4 + r) * 68 + wn * 32 + nt * 16 + l15] =
              acc[mt][nt][r];
  }
  __syncthreads();
  if (grp == 1) {
#pragma unroll
    for (int mt = 0; mt < 2; mt++)
#pragma unroll
      for (int nt = 0; nt < 2; nt++)
#pragma unroll
        for (int r = 0; r < 4; r++)
          ots[(wm * 32 + mt * 16 + quad * 4 + r) * 68 + wn * 32 + nt * 16 + l15] +=
              acc[mt][nt][r];
  }
  __syncthreads();
  // ---- residual + LN2 -> x1 + xs (+ x2f fp32 for head) ----
  for (int i = 0; i < 8; i++) {
    int row = wave * 8 + i;
    size_t off = (size_t)(bx * 64 + row) * 64 + lane;
    float val = ots[row * 68 + lane] + x2f[row * 64 + lane];
    float sum = val;
#pragma unroll
    for (int o = 32; o > 0; o >>= 1) sum += __shfl_xor(sum, o);
    float mean = sum * (1.f / 64.f);
    float d = val - mean;
    float sq = d * d;
#pragma unroll
    for (int o = 32; o > 0; o >>= 1) sq += __shfl_xor(sq, o);
    float xv = d * rsqrtf(sq * (1.f / 64.f) + 1e-5f) * ln2_s[lane] + ln2_b[lane];
    x1[off] = xv;
    x2f[row * 64 + lane] = xv;
    xs[SW64(row, lane)] = (_Float16)xv;
  }
  if (!doqkv) {
    // ---- head, fused into the last layer: only blocks owning t==15 rows ----
    __syncthreads();
    if ((bx & 15) == 15 && tid < 192) {
      int b = bx >> 4;
      int v = tid / 3, j = tid - v * 3;
      float a = bh[j];
      for (int e = 0; e < 64; e++)
        a += x2f[v * 64 + e] * Wh[e * 3 + j];
      out[((size_t)(b * 64 + v)) * 3 + j] = a;
    }
    return;
  }
  __syncthreads();
  // ---- next layer's QKV (grp0: nb 0,2; grp1: nb 1) ----
  half8 af[2][2];
#pragma unroll
  for (int mt = 0; mt < 2; mt++)
#pragma unroll
    for (int ks = 0; ks < 2; ks++)
      af[mt][ks] = *(const half8*)&xs[SW64(wm * 32 + mt * 16 + l15,
                                           ks * 32 + quad * 8)];
  for (int nb = grp; nb < 3; nb += 2)
    qkv_nb(af, wqkvf, bqkv, qbuf, kbuf, vbuf, bx, nb, wm, wn, lane);
}

extern "C" void kernel_launch(void* const* d_in, const int* in_sizes, int n_in,
                              void* d_out, int out_size, void* d_ws, size_t ws_size,
                              hipStream_t stream) {
  const float* features = (const float*)d_in[0];
  const int*   ovtag    = (const int*)d_in[1];
  const int*   poiid    = (const int*)d_in[2];
  const float* W_raw    = (const float*)d_in[3];
  const float* b_raw    = (const float*)d_in[4];
  const float* pos_tab  = (const float*)d_in[5];
  const float* type_tab = (const float*)d_in[6];
  const float* poi_tab  = (const float*)d_in[7];
  const float* ov_tab   = (const float*)d_in[8];
  const float* W_comb   = (const float*)d_in[9];
  const float* b_comb   = (const float*)d_in[10];
  const float* Wqkv     = (const float*)d_in[11];
  const float* bqkv     = (const float*)d_in[12];
  const float* Wo       = (const float*)d_in[13];
  const float* bo       = (const float*)d_in[14];
  const float* ln1_s    = (const float*)d_in[15];
  const float* ln1_b    = (const float*)d_in[16];
  const float* W1       = (const float*)d_in[17];
  const float* b1       = (const float*)d_in[18];
  const float* W2       = (const float*)d_in[19];
  const float* b2       = (const float*)d_in[20];
  const float* ln2_s    = (const float*)d_in[21];
  const float* ln2_b    = (const float*)d_in[22];
  const float* W_head   = (const float*)d_in[23];
  const float* b_head   = (const float*)d_in[24];
  float* out = (float*)d_out;
  float* ws  = (float*)d_ws;

  float* zm  = ws;                              // BL
  float* x1  = zm + BL;                         // BL*64
  _Float16* qbuf   = (_Float16*)(x1 + (size_t)BL * 64);       // BL*64 (head-major)
  _Float16* kbuf   = qbuf + (size_t)BL * 64;                  // BL*64 (head-major)
  _Float16* vbuf   = kbuf + (size_t)BL * 64;                  // BL*64 (head-major)
  _Float16* obuf16 = vbuf + (size_t)BL * 64;                  // BL*64 (frag-linear)
  _Float16* wcombt = obuf16 + (size_t)BL * 64;                // 64*80
  _Float16* w1f    = wcombt + 5120;                           // NL*PERL
  _Float16* w2f    = w1f + (size_t)NLAYER * PERL;             // NL*PERL
  _Float16* wqkvf  = w2f + (size_t)NLAYER * PERL;             // NL*3*4096
  _Float16* wof    = wqkvf + (size_t)NLAYER * 3 * 4096;       // NL*4096

  k_prep<<<274, 256, 0, stream>>>(W1, W2, Wqkv, Wo, W_comb,
                                  w1f, w2f, wqkvf, wof, wcombt);
  k_embqkv<<<256, 256, 0, stream>>>(features, ovtag, poiid, W_raw, b_raw,
                                    ov_tab, poi_tab, wcombt, b_comb,
                                    pos_tab, type_tab, x1, zm,
                                    wqkvf, bqkv, qbuf, kbuf, vbuf);
  for (int l = 0; l < NLAYER; l++) {
    k_attn2<<<512, 256, 0, stream>>>(qbuf, kbuf, vbuf, zm, obuf16);
    int doqkv = (l < NLAYER - 1);
    k_layer<<<256, 512, 0, stream>>>(
        obuf16, wof + (size_t)l * 4096, bo + l * EE, x1,
        ln1_s + l * EE, ln1_b + l * EE,
        w1f + (size_t)l * PERL, w2f + (size_t)l * PERL,
        b1 + l * DFF_, b2 + l * EE,
        ln2_s + l * EE, ln2_b + l * EE,
        wqkvf + (size_t)(l + 1 < NLAYER ? l + 1 : 0) * 3 * 4096,
        bqkv + (l + 1 < NLAYER ? l + 1 : 0) * 192,
        qbuf, kbuf, vbuf, doqkv, W_head, b_head, out);
  }
}

// Round 11
// 309.004 us; speedup vs baseline: 1.0273x; 1.0273x over previous
//
#include <hip/hip_runtime.h>
#include <math.h>

#define BB 16
#define SS 16
#define VVV 64
#define EE 64
#define HHH 8
#define NLAYER 4
#define DFF_ 2048
#define LL 1024   /* S*V */
#define BL 16384  /* B*L */
#define PERL 131072  /* 64*2048 elems per layer of W1 (and W2); 32 tiles*4096 */

typedef __attribute__((ext_vector_type(8))) _Float16 half8;
typedef __attribute__((ext_vector_type(4))) _Float16 half4v;
typedef __attribute__((ext_vector_type(2))) _Float16 half2v;
typedef __attribute__((ext_vector_type(4))) float f32x4;

#if defined(__has_builtin)
#if __has_builtin(__builtin_amdgcn_fdot2)
#define HAVE_FDOT2 1
#endif
#endif

// XOR-swizzled index into row-major fp16 LDS tiles with 64-half (128 B) rows.
#define SW64(m, k)  (((m) << 6) + ((((k) >> 3) ^ ((m) & 7)) << 3) + ((k) & 7))

// Fragment-linear tile layout (64x64 fp16 = 8 frags of 512 halves):
//   A[m][k] -> frag = (m>>4)*2 + (k>>5); lane = ((k>>3)&3)*16 + (m&15); +(k&7)

// ---------------- prep: weights -> fp16 fragment-linear tiles (one dispatch) ----------
__global__ __launch_bounds__(256) void k_prep(
    const float* __restrict__ W1, const float* __restrict__ W2,
    const float* __restrict__ Wqkv, const float* __restrict__ Wo,
    const float* __restrict__ Wcomb,
    _Float16* __restrict__ w1f, _Float16* __restrict__ w2f,
    _Float16* __restrict__ wqkvf, _Float16* __restrict__ wof,
    _Float16* __restrict__ wcombt)
{
  __shared__ float t[64 * 65];
  int bx = blockIdx.x;
  int cc = threadIdx.x & 63, rr = threadIdx.x >> 6;

  if (bx >= 272) {  // Wcomb [80][64] -> wcombt [64][80]
    int r0 = (bx - 272) * 64;
#pragma unroll
    for (int i = 0; i < 16; i++) {
      int r = i * 4 + rr;
      if (r0 + r < 80) t[r * 65 + cc] = Wcomb[(size_t)(r0 + r) * 64 + cc];
    }
    __syncthreads();
#pragma unroll
    for (int i = 0; i < 16; i++) {
      int c = i * 4 + rr;
      if (r0 + c < 80) wcombt[(size_t)cc * 80 + r0 + c] = (_Float16)t[c * 65 + cc];
    }
    return;
  }

  const float* src; _Float16* dst; int astr;
  if (bx < 128) {        // W1 [64 k][2048 hid]: tile g = hid block
    int l = bx >> 5, g = bx & 31;
    src = W1 + (size_t)l * PERL + g * 64; astr = 2048;
    dst = w1f + (size_t)(l * 32 + g) * 4096;
  } else if (bx < 256) { // W2 [2048 k][64 n]: tile g = k block
    int j = bx - 128; int l = j >> 5, g = j & 31;
    src = W2 + (size_t)l * PERL + (size_t)g * 64 * 64; astr = 64;
    dst = w2f + (size_t)(l * 32 + g) * 4096;
  } else if (bx < 268) { // Wqkv [64 k][192 n]: 3 tiles per layer
    int j = bx - 256; int l = j / 3, g = j % 3;
    src = Wqkv + (size_t)l * 64 * 192 + g * 64; astr = 192;
    dst = wqkvf + (size_t)(l * 3 + g) * 4096;
  } else {               // Wo [64 k][64 n]
    int l = bx - 268;
    src = Wo + (size_t)l * 4096; astr = 64;
    dst = wof + (size_t)l * 4096;
  }
#pragma unroll
  for (int i = 0; i < 16; i++) {
    int a = i * 4 + rr;
    t[cc * 65 + a] = src[(size_t)a * astr + cc];  // t[m][k] = S[k][m]
  }
  __syncthreads();
#pragma unroll
  for (int it = 0; it < 2; it++) {
    int c = threadIdx.x + it * 256;
    int frag = c >> 6, lane = c & 63;
    int m = (frag >> 1) * 16 + (lane & 15);
    int k0 = (frag & 1) * 32 + (lane >> 4) * 8;
    const float* tr = &t[m * 65 + k0];
    half8 h;
#pragma unroll
    for (int j = 0; j < 8; j++) h[j] = (_Float16)tr[j];
    *(half8*)&dst[(size_t)c * 8] = h;
  }
}

// ---- QKV GEMM body (64-row blocks, 4 waves m2xn2) for embqkv; head-major stores ----
__device__ __forceinline__ void qkv_nb(
    const half8 (&af)[2][2], const _Float16* __restrict__ wqkvf,
    const float* __restrict__ bqkv, _Float16* __restrict__ qbuf,
    _Float16* __restrict__ kbuf, _Float16* __restrict__ vbuf,
    int bx, int nb, int wm, int wn, int lane)
{
  int quad = lane >> 4, l15 = lane & 15;
  const _Float16* bt = wqkvf + (size_t)nb * 4096;
  half8 bf[2][2];
#pragma unroll
  for (int nt = 0; nt < 2; nt++)
#pragma unroll
    for (int ks = 0; ks < 2; ks++)
      bf[nt][ks] = *(const half8*)&bt[(size_t)(((wn * 2 + nt) * 2 + ks) * 512) +
                                      lane * 8];
  f32x4 acc[2][2];
#pragma unroll
  for (int mt = 0; mt < 2; mt++)
#pragma unroll
    for (int nt = 0; nt < 2; nt++) {
      float bv = bqkv[nb * 64 + wn * 32 + nt * 16 + l15];
      acc[mt][nt] = (f32x4){bv, bv, bv, bv};
    }
#pragma unroll
  for (int ks = 0; ks < 2; ks++)
#pragma unroll
    for (int mt = 0; mt < 2; mt++)
#pragma unroll
      for (int nt = 0; nt < 2; nt++)
        acc[mt][nt] = __builtin_amdgcn_mfma_f32_16x16x32_f16(
            af[mt][ks], bf[nt][ks], acc[mt][nt], 0, 0, 0);
  _Float16* dst = (nb == 0) ? qbuf : ((nb == 1) ? kbuf : vbuf);
#pragma unroll
  for (int mt = 0; mt < 2; mt++)
#pragma unroll
    for (int nt = 0; nt < 2; nt++) {
      int col = wn * 32 + nt * 16 + l15;
      int h = col >> 3, d = col & 7;
#pragma unroll
      for (int r = 0; r < 4; r++) {
        int row = bx * 64 + wm * 32 + mt * 16 + quad * 4 + r;
        int b = row >> 10, rb = row & 1023;
        dst[((size_t)(b * 8 + h) * 1024 + rb) * 8 + d] = (_Float16)acc[mt][nt][r];
      }
    }
}

// ---- FFN helpers for 32-row blocks (2 waves per group; wn = wave-in-group) ----
__device__ __forceinline__ void ffn_load2(
    const _Float16* __restrict__ w1f, const _Float16* __restrict__ w2f, int g,
    half8 (&a1)[2][2], half8 (&b2w)[2][2], int wn, int lane)
{
  const _Float16* w1t_ = w1f + (size_t)g * 4096;
  const _Float16* w2t_ = w2f + (size_t)g * 4096;
#pragma unroll
  for (int ht = 0; ht < 2; ht++)
#pragma unroll
    for (int ks = 0; ks < 2; ks++)
      a1[ht][ks] = *(const half8*)&w1t_[(size_t)(((wn * 2 + ht) * 2 + ks) * 512) +
                                        lane * 8];
#pragma unroll
  for (int nt = 0; nt < 2; nt++)
#pragma unroll
    for (int ks = 0; ks < 2; ks++)
      b2w[nt][ks] = *(const half8*)&w2t_[(size_t)(((wn * 2 + nt) * 2 + ks) * 512) +
                                         lane * 8];
}

__device__ __forceinline__ void ffn_step2(
    const half8 (&a1)[2][2], const half8 (&b2w)[2][2], const half8 (&xb)[2][2],
    _Float16* hsbuf, const float* __restrict__ b1, int g, f32x4 (&acc)[2][2],
    int wn, int lane)
{
  int quad = lane >> 4, l15 = lane & 15;
  f32x4 hacc[2][2];
#pragma unroll
  for (int ht = 0; ht < 2; ht++)
#pragma unroll
    for (int mt = 0; mt < 2; mt++) hacc[ht][mt] = (f32x4){0.f, 0.f, 0.f, 0.f};
#pragma unroll
  for (int ks = 0; ks < 2; ks++)
#pragma unroll
    for (int ht = 0; ht < 2; ht++)
#pragma unroll
      for (int mt = 0; mt < 2; mt++)
        hacc[ht][mt] = __builtin_amdgcn_mfma_f32_16x16x32_f16(
            a1[ht][ks], xb[mt][ks], hacc[ht][mt], 0, 0, 0);
#pragma unroll
  for (int ht = 0; ht < 2; ht++) {
    float4 bb = *(const float4*)&b1[g * 64 + wn * 32 + ht * 16 + quad * 4];
#pragma unroll
    for (int mt = 0; mt < 2; mt++) {
      f32x4 hv = hacc[ht][mt];
      half4v hp = (half4v){
          (_Float16)fmaxf(hv[0] + bb.x, 0.f), (_Float16)fmaxf(hv[1] + bb.y, 0.f),
          (_Float16)fmaxf(hv[2] + bb.z, 0.f), (_Float16)fmaxf(hv[3] + bb.w, 0.f)};
      *(half4v*)&hsbuf[SW64(mt * 16 + l15, wn * 32 + ht * 16 + quad * 4)] = hp;
    }
  }
  __syncthreads();
#pragma unroll
  for (int ks = 0; ks < 2; ks++)
#pragma unroll
    for (int mt = 0; mt < 2; mt++) {
      half8 a2 = *(const half8*)&hsbuf[SW64(mt * 16 + l15, ks * 32 + quad * 8)];
#pragma unroll
      for (int nt = 0; nt < 2; nt++)
        acc[mt][nt] = __builtin_amdgcn_mfma_f32_16x16x32_f16(a2, b2w[nt][ks],
                                                             acc[mt][nt], 0, 0, 0);
    }
}

// ------- fused embed + comb GEMM + pos/type + QKV(layer0): writes x1, zm, q/k/v -------
__global__ __launch_bounds__(256) void k_embqkv(
    const float* __restrict__ features, const int* __restrict__ ovtag,
    const int* __restrict__ poiid, const float* __restrict__ W_raw,
    const float* __restrict__ b_raw, const float* __restrict__ ov_tab,
    const float* __restrict__ poi_tab, const _Float16* __restrict__ wcombt,
    const float* __restrict__ b_comb, const float* __restrict__ pos_tab,
    const float* __restrict__ type_tab, float* __restrict__ x1,
    float* __restrict__ zm, const _Float16* __restrict__ wqkvf,
    const float* __restrict__ bqkv, _Float16* __restrict__ qbuf,
    _Float16* __restrict__ kbuf, _Float16* __restrict__ vbuf)
{
  constexpr int KP = 104;
  __shared__ _Float16 As[64 * KP];
  __shared__ _Float16 Bs[64 * KP];
  __shared__ _Float16 xs[4096];
  int tid = threadIdx.x;
  int bx = blockIdx.x;
  int m0 = bx * 64;
  int wave = tid >> 6, lane = tid & 63, quad = lane >> 4, l15 = lane & 15;
  int wm = wave >> 1, wn = wave & 1;
  for (int p = tid; p < 1536; p += 256) {
    int r = p / 24, s = p - r * 24; int c = s * 4;
    int row = m0 + r;
    float f0 = features[row * 3 + 0];
    float f1 = features[row * 3 + 1];
    float f2 = features[row * 3 + 2];
    if (s == 0) zm[row] = ((f0 + f1 + f2) == 0.f) ? 1.f : 0.f;
    half4v h;
#pragma unroll
    for (int j = 0; j < 4; j++) {
      int cc = c + j; float v;
      if (cc < 64) {
        v = b_raw[cc] + f0 * W_raw[cc] + f1 * W_raw[64 + cc] + f2 * W_raw[128 + cc];
      } else if (cc < 72) {
        int tt = ovtag[row]; v = (tt <= 0) ? 0.f : ov_tab[tt * 8 + cc - 64];
      } else if (cc < 80) {
        int tt = poiid[row]; v = (tt <= 0) ? 0.f : poi_tab[tt * 8 + cc - 72];
      } else v = 0.f;
      h[j] = (_Float16)v;
    }
    *(half4v*)&As[r * KP + c] = h;
  }
  for (int p = tid; p < 1536; p += 256) {
    int r = p / 24, s = p - r * 24; int c = s * 4;
    half4v h = (half4v){0, 0, 0, 0};
    if (c < 80) h = *(const half4v*)&wcombt[r * 80 + c];
    *(half4v*)&Bs[r * KP + c] = h;
  }
  __syncthreads();
  f32x4 acc[2][2];
#pragma unroll
  for (int mt = 0; mt < 2; mt++)
#pragma unroll
    for (int nt = 0; nt < 2; nt++) {
      float bv = b_comb[wn * 32 + nt * 16 + l15];
      acc[mt][nt] = (f32x4){bv, bv, bv, bv};
    }
#pragma unroll
  for (int ks = 0; ks < 3; ks++) {
    half8 af[2], bf[2];
#pragma unroll
    for (int mt = 0; mt < 2; mt++)
      af[mt] = *(const half8*)&As[(wm * 32 + mt * 16 + l15) * KP + ks * 32 + quad * 8];
#pragma unroll
    for (int nt = 0; nt < 2; nt++)
      bf[nt] = *(const half8*)&Bs[(wn * 32 + nt * 16 + l15) * KP + ks * 32 + quad * 8];
#pragma unroll
    for (int mt = 0; mt < 2; mt++)
#pragma unroll
      for (int nt = 0; nt < 2; nt++)
        acc[mt][nt] = __builtin_amdgcn_mfma_f32_16x16x32_f16(af[mt], bf[nt],
                                                             acc[mt][nt], 0, 0, 0);
  }
#pragma unroll
  for (int mt = 0; mt < 2; mt++)
#pragma unroll
    for (int nt = 0; nt < 2; nt++)
#pragma unroll
      for (int r = 0; r < 4; r++) {
        int lrow = wm * 32 + mt * 16 + quad * 4 + r;
        int row = m0 + lrow;
        int col = wn * 32 + nt * 16 + l15;
        int l = row & (LL - 1);
        float v = acc[mt][nt][r] +
            pos_tab[(l >> 6) * 64 + col] + type_tab[(l & 63) * 64 + col];
        x1[(size_t)row * 64 + col] = v;
        xs[SW64(lrow, col)] = (_Float16)v;
      }
  __syncthreads();
  half8 af[2][2];
#pragma unroll
  for (int mt = 0; mt < 2; mt++)
#pragma unroll
    for (int ks = 0; ks < 2; ks++)
      af[mt][ks] = *(const half8*)&xs[SW64(wm * 32 + mt * 16 + l15,
                                           ks * 32 + quad * 8)];
  for (int nb = 0; nb < 3; nb++)
    qkv_nb(af, wqkvf, bqkv, qbuf, kbuf, vbuf, bx, nb, wm, wn, lane);
}

// ------- attention: 1024 blocks x 128 thr (4 blocks/CU); branchless online softmax -------
__global__ __launch_bounds__(128) void k_attn3(
    const _Float16* __restrict__ qbuf, const _Float16* __restrict__ kbuf,
    const _Float16* __restrict__ vbuf, const float* __restrict__ zm,
    _Float16* __restrict__ obuf)
{
  __shared__ _Float16 Ks[1024 * 8];
  __shared__ _Float16 Vs[1024 * 8];
  __shared__ float zs[1024];
  int blk = blockIdx.x;
  int qb = blk & 7, h = (blk >> 3) & 7, b = blk >> 6;
  int qrow = qb * 128 + threadIdx.x;
  half8 qh = *(const half8*)&qbuf[(size_t)(b * 8 + h) * 8192 + (size_t)qrow * 8];
  const _Float16* kb = kbuf + (size_t)(b * 8 + h) * 8192;
  const _Float16* vb = vbuf + (size_t)(b * 8 + h) * 8192;
  for (int p = threadIdx.x; p < 1024; p += 128) {
    *(half8*)&Ks[p * 8] = *(const half8*)&kb[p * 8];
    *(half8*)&Vs[p * 8] = *(const half8*)&vb[p * 8];
    zs[p] = zm[b * LL + p];
  }
  __syncthreads();
  int tq = qrow >> 6, vq = qrow & 63;
  const float scale = 0.3535533905932738f;
  float m = -INFINITY, lsum = 0.f;
  float acc[8] = {0.f, 0.f, 0.f, 0.f, 0.f, 0.f, 0.f, 0.f};
  bool zmq = (zs[qrow] != 0.f);

  auto attend = [&](int k) {
    if (zs[k] != 0.f) return;
    half8 kk = *(const half8*)&Ks[k * 8];
    float s = 0.f;
#ifdef HAVE_FDOT2
#pragma unroll
    for (int j = 0; j < 4; j++) {
      half2v qa = (half2v){qh[2 * j], qh[2 * j + 1]};
      half2v ka = (half2v){kk[2 * j], kk[2 * j + 1]};
      s = __builtin_amdgcn_fdot2(qa, ka, s, false);
    }
#else
#pragma unroll
    for (int j = 0; j < 8; j++) s += (float)qh[j] * (float)kk[j];
#endif
    s *= scale;
    half8 vv = *(const half8*)&Vs[k * 8];
    // branchless online softmax update
    float nm = fmaxf(m, s);
    float r = __expf(m - nm);   // m=-inf first time -> 0
    float p = __expf(s - nm);
    lsum = lsum * r + p;
#pragma unroll
    for (int d = 0; d < 8; d++) acc[d] = acc[d] * r + p * (float)vv[d];
    m = nm;
  };

  if (!zmq) {
    for (int vv = 0; vv < 64; vv++) attend(tq * 64 + vv);   // wave-uniform k
    for (int tt = 0; tt < 16; tt++) {
      if (tt == tq) continue;
      attend(tt * 64 + vq);
    }
  }
  float inv = 1.f / lsum;
  half8 o;
#pragma unroll
  for (int d = 0; d < 8; d++) o[d] = (_Float16)(acc[d] * inv);
  size_t tile = (size_t)(b * 16 + (qrow >> 6));
  int frag = ((qrow >> 4) & 3) * 2 + (h >> 2);
  int flane = (h & 3) * 16 + (qrow & 15);
  *(half8*)&obuf[tile * 4096 + frag * 512 + flane * 8] = o;
}

// ---- layer kernel: 512 blocks x 256 thr, 32 rows/block (2 resident blocks/CU) ----
__global__ __launch_bounds__(256, 2) void k_layer2(
    const _Float16* __restrict__ obuf, const _Float16* __restrict__ wof,
    const float* __restrict__ bo, float* __restrict__ x1,
    const float* __restrict__ ln1_s, const float* __restrict__ ln1_b,
    const _Float16* __restrict__ w1f, const _Float16* __restrict__ w2f,
    const float* __restrict__ b1, const float* __restrict__ b2,
    const float* __restrict__ ln2_s, const float* __restrict__ ln2_b,
    const _Float16* __restrict__ wqkvf, const float* __restrict__ bqkv,
    _Float16* __restrict__ qbuf, _Float16* __restrict__ kbuf,
    _Float16* __restrict__ vbuf, int doqkv,
    const float* __restrict__ Wh, const float* __restrict__ bh,
    float* __restrict__ out)
{
  __shared__ float ots[32 * 68];          // 8.7 KB
  __shared__ _Float16 xs[2048];           // 4 KB  (post-LN fp16, 32x64)
  __shared__ float x2f[2048];             // 8 KB  (fp32 residual / head input)
  __shared__ _Float16 hs[2][2][2048];     // 16 KB ([grp][dbuf] 32m x 64h)
  int tid = threadIdx.x;
  int bx = blockIdx.x;                    // 32-row tile index
  int r0 = bx * 32;
  int wave = tid >> 6, lane = tid & 63;
  int quad = lane >> 4, l15 = lane & 15;
  int grp = wave >> 1, wn = wave & 1;

  // ---- o-proj: wave covers m-tile (grp) x n-half (wn); obuf tile = bx>>1 ----
  {
    const _Float16* ot = obuf + (size_t)(bx >> 1) * 4096;
    int mt_g = (bx & 1) * 2 + grp;        // global m-16-tile within 64-row obuf tile
    half8 af[2], bf[2][2];
#pragma unroll
    for (int ks = 0; ks < 2; ks++)
      af[ks] = *(const half8*)&ot[(size_t)((mt_g * 2 + ks) * 512) + lane * 8];
#pragma unroll
    for (int nt = 0; nt < 2; nt++)
#pragma unroll
      for (int ks = 0; ks < 2; ks++)
        bf[nt][ks] = *(const half8*)&wof[(size_t)(((wn * 2 + nt) * 2 + ks) * 512) +
                                         lane * 8];
    f32x4 acc[2];
#pragma unroll
    for (int nt = 0; nt < 2; nt++) {
      float bv = bo[wn * 32 + nt * 16 + l15];
      acc[nt] = (f32x4){bv, bv, bv, bv};
    }
#pragma unroll
    for (int ks = 0; ks < 2; ks++)
#pragma unroll
      for (int nt = 0; nt < 2; nt++)
        acc[nt] = __builtin_amdgcn_mfma_f32_16x16x32_f16(af[ks], bf[nt][ks],
                                                         acc[nt], 0, 0, 0);
#pragma unroll
    for (int nt = 0; nt < 2; nt++)
#pragma unroll
      for (int r = 0; r < 4; r++)
        ots[(grp * 16 + quad * 4 + r) * 68 + wn * 32 + nt * 16 + l15] = acc[nt][r];
  }
  __syncthreads();
  // ---- residual + LN1 (4 waves x 8 rows) ----
  for (int i = 0; i < 8; i++) {
    int row = wave * 8 + i;
    size_t off = (size_t)(r0 + row) * 64 + lane;
    float val = ots[row * 68 + lane] + x1[off];
    float sum = val;
#pragma unroll
    for (int o = 32; o > 0; o >>= 1) sum += __shfl_xor(sum, o);
    float mean = sum * (1.f / 64.f);
    float d = val - mean;
    float sq = d * d;
#pragma unroll
    for (int o = 32; o > 0; o >>= 1) sq += __shfl_xor(sq, o);
    float xv = d * rsqrtf(sq * (1.f / 64.f) + 1e-5f) * ln1_s[lane] + ln1_b[lane];
    x2f[row * 64 + lane] = xv;
    xs[SW64(row, lane)] = (_Float16)xv;
  }
  __syncthreads();

  // ---- FFN: group g handles chunks 2i+g (16 chunks); explicit 2-stage pipeline ----
  half8 xb[2][2];
#pragma unroll
  for (int mt = 0; mt < 2; mt++)
#pragma unroll
    for (int ks = 0; ks < 2; ks++)
      xb[mt][ks] = *(const half8*)&xs[SW64(mt * 16 + l15, ks * 32 + quad * 8)];
  f32x4 acc[2][2];
#pragma unroll
  for (int mt = 0; mt < 2; mt++)
#pragma unroll
    for (int nt = 0; nt < 2; nt++) {
      float bv = (grp == 0) ? b2[wn * 32 + nt * 16 + l15] : 0.f;
      acc[mt][nt] = (f32x4){bv, bv, bv, bv};
    }
  half8 a1x[2][2], b2x[2][2], a1y[2][2], b2y[2][2];
  ffn_load2(w1f, w2f, grp, a1x, b2x, wn, lane);
  for (int ii = 0; ii < 8; ii++) {
    ffn_load2(w1f, w2f, ii * 4 + 2 + grp, a1y, b2y, wn, lane);
    ffn_step2(a1x, b2x, xb, &hs[grp][0][0], b1, ii * 4 + grp, acc, wn, lane);
    if (ii < 7) ffn_load2(w1f, w2f, ii * 4 + 4 + grp, a1x, b2x, wn, lane);
    ffn_step2(a1y, b2y, xb, &hs[grp][1][0], b1, ii * 4 + 2 + grp, acc, wn, lane);
  }
  // ---- cross-group reduce into ots ----
  __syncthreads();
  if (grp == 0) {
#pragma unroll
    for (int mt = 0; mt < 2; mt++)
#pragma unroll
      for (int nt = 0; nt < 2; nt++)
#pragma unroll
        for (int r = 0; r < 4; r++)
          ots[(mt * 16 + quad * 4 + r) * 68 + wn * 32 + nt * 16 + l15] =
              acc[mt][nt][r];
  }
  __syncthreads();
  if (grp == 1) {
#pragma unroll
    for (int mt = 0; mt < 2; mt++)
#pragma unroll
      for (int nt = 0; nt < 2; nt++)
#pragma unroll
        for (int r = 0; r < 4; r++)
          ots[(mt * 16 + quad * 4 + r) * 68 + wn * 32 + nt * 16 + l15] +=
              acc[mt][nt][r];
  }
  __syncthreads();
  // ---- residual + LN2 -> x1 + xs (+ x2f fp32 for head) ----
  for (int i = 0; i < 8; i++) {
    int row = wave * 8 + i;
    size_t off = (size_t)(r0 + row) * 64 + lane;
    float val = ots[row * 68 + lane] + x2f[row * 64 + lane];
    float sum = val;
#pragma unroll
    for (int o = 32; o > 0; o >>= 1) sum += __shfl_xor(sum, o);
    float mean = sum * (1.f / 64.f);
    float d = val - mean;
    float sq = d * d;
#pragma unroll
    for (int o = 32; o > 0; o >>= 1) sq += __shfl_xor(sq, o);
    float xv = d * rsqrtf(sq * (1.f / 64.f) + 1e-5f) * ln2_s[lane] + ln2_b[lane];
    x1[off] = xv;
    x2f[row * 64 + lane] = xv;
    xs[SW64(row, lane)] = (_Float16)xv;
  }
  if (!doqkv) {
    // ---- fused head: blocks owning t==15 rows: bx%32 in {30,31} ----
    __syncthreads();
    if ((bx & 31) >= 30 && tid < 96) {
      int b = bx >> 5;
      int i = tid / 3, j = tid - i * 3;
      int vglob = (bx & 1) * 32 + i;
      float a = bh[j];
      for (int e = 0; e < 64; e++)
        a += x2f[i * 64 + e] * Wh[e * 3 + j];
      out[((size_t)(b * 64 + vglob)) * 3 + j] = a;
    }
    return;
  }
  __syncthreads();
  // ---- next layer's QKV: wave w covers n-16-tile w of each nb; m = 32 rows ----
  half8 af[2][2];
#pragma unroll
  for (int mt = 0; mt < 2; mt++)
#pragma unroll
    for (int ks = 0; ks < 2; ks++)
      af[mt][ks] = *(const half8*)&xs[SW64(mt * 16 + l15, ks * 32 + quad * 8)];
  for (int nb = 0; nb < 3; nb++) {
    const _Float16* bt = wqkvf + (size_t)nb * 4096;
    half8 bf[2];
#pragma unroll
    for (int ks = 0; ks < 2; ks++)
      bf[ks] = *(const half8*)&bt[(size_t)((wave * 2 + ks) * 512) + lane * 8];
    f32x4 qacc[2];
#pragma unroll
    for (int mt = 0; mt < 2; mt++) {
      float bv = bqkv[nb * 64 + wave * 16 + l15];
      qacc[mt] = (f32x4){bv, bv, bv, bv};
    }
#pragma unroll
    for (int ks = 0; ks < 2; ks++)
#pragma unroll
      for (int mt = 0; mt < 2; mt++)
        qacc[mt] = __builtin_amdgcn_mfma_f32_16x16x32_f16(af[mt][ks], bf[ks],
                                                          qacc[mt], 0, 0, 0);
    _Float16* dst = (nb == 0) ? qbuf : ((nb == 1) ? kbuf : vbuf);
    int col = wave * 16 + l15;
    int h = col >> 3, d = col & 7;
#pragma unroll
    for (int mt = 0; mt < 2; mt++)
#pragma unroll
      for (int r = 0; r < 4; r++) {
        int row = r0 + mt * 16 + quad * 4 + r;
        int b = row >> 10, rb = row & 1023;
        dst[((size_t)(b * 8 + h) * 1024 + rb) * 8 + d] = (_Float16)qacc[mt][r];
      }
  }
}

extern "C" void kernel_launch(void* const* d_in, const int* in_sizes, int n_in,
                              void* d_out, int out_size, void* d_ws, size_t ws_size,
                              hipStream_t stream) {
  const float* features = (const float*)d_in[0];
  const int*   ovtag    = (const int*)d_in[1];
  const int*   poiid    = (const int*)d_in[2];
  const float* W_raw    = (const float*)d_in[3];
  const float* b_raw    = (const float*)d_in[4];
  const float* pos_tab  = (const float*)d_in[5];
  const float* type_tab = (const float*)d_in[6];
  const float* poi_tab  = (const float*)d_in[7];
  const float* ov_tab   = (const float*)d_in[8];
  const float* W_comb   = (const float*)d_in[9];
  const float* b_comb   = (const float*)d_in[10];
  const float* Wqkv     = (const float*)d_in[11];
  const float* bqkv     = (const float*)d_in[12];
  const float* Wo       = (const float*)d_in[13];
  const float* bo       = (const float*)d_in[14];
  const float* ln1_s    = (const float*)d_in[15];
  const float* ln1_b    = (const float*)d_in[16];
  const float* W1       = (const float*)d_in[17];
  const float* b1       = (const float*)d_in[18];
  const float* W2       = (const float*)d_in[19];
  const float* b2       = (const float*)d_in[20];
  const float* ln2_s    = (const float*)d_in[21];
  const float* ln2_b    = (const float*)d_in[22];
  const float* W_head   = (const float*)d_in[23];
  const float* b_head   = (const float*)d_in[24];
  float* out = (float*)d_out;
  float* ws  = (float*)d_ws;

  float* zm  = ws;                              // BL
  float* x1  = zm + BL;                         // BL*64
  _Float16* qbuf   = (_Float16*)(x1 + (size_t)BL * 64);       // BL*64 (head-major)
  _Float16* kbuf   = qbuf + (size_t)BL * 64;                  // BL*64 (head-major)
  _Float16* vbuf   = kbuf + (size_t)BL * 64;                  // BL*64 (head-major)
  _Float16* obuf16 = vbuf + (size_t)BL * 64;                  // BL*64 (frag-linear)
  _Float16* wcombt = obuf16 + (size_t)BL * 64;                // 64*80
  _Float16* w1f    = wcombt + 5120;                           // NL*PERL
  _Float16* w2f    = w1f + (size_t)NLAYER * PERL;             // NL*PERL
  _Float16* wqkvf  = w2f + (size_t)NLAYER * PERL;             // NL*3*4096
  _Float16* wof    = wqkvf + (size_t)NLAYER * 3 * 4096;       // NL*4096

  k_prep<<<274, 256, 0, stream>>>(W1, W2, Wqkv, Wo, W_comb,
                                  w1f, w2f, wqkvf, wof, wcombt);
  k_embqkv<<<256, 256, 0, stream>>>(features, ovtag, poiid, W_raw, b_raw,
                                    ov_tab, poi_tab, wcombt, b_comb,
                                    pos_tab, type_tab, x1, zm,
                                    wqkvf, bqkv, qbuf, kbuf, vbuf);
  for (int l = 0; l < NLAYER; l++) {
    k_attn3<<<1024, 128, 0, stream>>>(qbuf, kbuf, vbuf, zm, obuf16);
    int doqkv = (l < NLAYER - 1);
    k_layer2<<<512, 256, 0, stream>>>(
        obuf16, wof + (size_t)l * 4096, bo + l * EE, x1,
        ln1_s + l * EE, ln1_b + l * EE,
        w1f + (size_t)l * PERL, w2f + (size_t)l * PERL,
        b1 + l * DFF_, b2 + l * EE,
        ln2_s + l * EE, ln2_b + l * EE,
        wqkvf + (size_t)(l + 1 < NLAYER ? l + 1 : 0) * 3 * 4096,
        bqkv + (l + 1 < NLAYER ? l + 1 : 0) * 192,
        qbuf, kbuf, vbuf, doqkv, W_head, b_head, out);
  }
}